// Round 1
// baseline (28.321 us; speedup 1.0000x reference)
//
#include <hip/hip_runtime.h>
#include <hip/hip_bf16.h>
#include <math.h>

// One wave (64 lanes) per (batch, request) pair.
// Each lane holds 8 contiguous floats of x[b] (two float4 loads).
// Per path node: gather W row (two float4 loads/lane), 8 FMAs, wave
// shuffle-reduce, sigmoid, multiply factor into running product.
#define WAVES_PER_BLOCK 4

__global__ __launch_bounds__(WAVES_PER_BLOCK * 64)
void huffmax_kernel(const float* __restrict__ x,     // (B, I)
                    const int*   __restrict__ tgt,   // (B, R)
                    const float* __restrict__ W,     // (N, I)
                    const float* __restrict__ bias,  // (N)
                    const int*   __restrict__ paths, // (C, D)
                    const float* __restrict__ codes, // (C, D)
                    float*       __restrict__ out,   // (B, R)
                    int B, int R, int D, int I)
{
    const int lane = threadIdx.x & 63;
    const int wave = threadIdx.x >> 6;
    const int p = blockIdx.x * WAVES_PER_BLOCK + wave;
    if (p >= B * R) return;
    const int b = p / R;

    // x row: I == 512 -> 8 floats per lane, coalesced 16B/lane.
    const float4* xrow = reinterpret_cast<const float4*>(x + (size_t)b * I);
    const float4 x0 = xrow[lane * 2 + 0];
    const float4 x1 = xrow[lane * 2 + 1];

    const int c = tgt[p];
    const int*   path = paths + (size_t)c * D;
    const float* code = codes + (size_t)c * D;

    float prod = 1.0f;
    for (int d = 0; d < D; ++d) {
        const int node = path[d];
        const float4* wrow = reinterpret_cast<const float4*>(W + (size_t)node * I);
        const float4 w0 = wrow[lane * 2 + 0];
        const float4 w1 = wrow[lane * 2 + 1];
        float acc = x0.x * w0.x + x0.y * w0.y + x0.z * w0.z + x0.w * w0.w
                  + x1.x * w1.x + x1.y * w1.y + x1.z * w1.z + x1.w * w1.w;
        #pragma unroll
        for (int off = 32; off; off >>= 1)
            acc += __shfl_xor(acc, off, 64);
        const float t = acc + bias[node];
        // accurate sigmoid in fp32 (threshold is ~3% relative of output scale)
        const float y = 1.0f / (1.0f + expf(-t));
        const float cd = code[d];
        prod *= cd + y - 2.0f * cd * y;   // y if code==0, (1-y) if code==1
    }
    if (lane == 0) out[p] = prod;
}

extern "C" void kernel_launch(void* const* d_in, const int* in_sizes, int n_in,
                              void* d_out, int out_size, void* d_ws, size_t ws_size,
                              hipStream_t stream) {
    const float* x     = (const float*)d_in[0];
    const int*   tgt   = (const int*)  d_in[1];
    const float* W     = (const float*)d_in[2];
    const float* bias  = (const float*)d_in[3];
    const int*   paths = (const int*)  d_in[4];
    const float* codes = (const float*)d_in[5];
    float* out = (float*)d_out;

    const int N = in_sizes[3];            // total_nodes = nb_classes - 1
    const int C = N + 1;                  // nb_classes
    const int I = in_sizes[2] / N;        // input dim (512)
    const int B = in_sizes[0] / I;        // batch (1024)
    const int R = in_sizes[1] / B;        // requests (8)
    const int D = in_sizes[4] / C;        // max path depth (~16)

    const int pairs = B * R;
    const int grid = (pairs + WAVES_PER_BLOCK - 1) / WAVES_PER_BLOCK;
    huffmax_kernel<<<grid, WAVES_PER_BLOCK * 64, 0, stream>>>(
        x, tgt, W, bias, paths, codes, out, B, R, D, I);
}

// Round 2
// 25.454 us; speedup vs baseline: 1.1126x; 1.1126x over previous
//
#include <hip/hip_runtime.h>
#include <math.h>

#define WPB 4   // waves per block

// One wave per (batch, request) pair. All D path-node ids / codes / biases
// are hoisted into lane registers before the main loop so every W-row load
// address is known up-front (max memory-level parallelism). D independent
// accumulators; one batched butterfly reduce; single division at the end:
//   prod_d sigmoid(s_d * t_d) = 1 / prod_d (1 + exp(-s_d * t_d)),  s_d = 1-2*code_d
template<int D>
__global__ __launch_bounds__(WPB * 64, 4)
void huff_kernel(const float* __restrict__ x,     // (B, I)
                 const int*   __restrict__ tgt,   // (B, R)
                 const float* __restrict__ W,     // (N, I)
                 const float* __restrict__ bias,  // (N)
                 const int*   __restrict__ paths, // (C, D)
                 const float* __restrict__ codes, // (C, D)
                 float*       __restrict__ out,   // (B, R)
                 int R, int I, int npairs)
{
    const int lane = threadIdx.x & 63;
    const int wv   = threadIdx.x >> 6;
    const int p    = blockIdx.x * WPB + wv;
    if (p >= npairs) return;
    const int b = p / R;

    // x row: I == 512 -> two fully-coalesced 1KB wave loads
    const float4* xrow = reinterpret_cast<const float4*>(x + (size_t)b * I);
    const float4 xa = xrow[lane];
    const float4 xb = xrow[lane + 64];

    const int c  = tgt[p];
    const int dd = (lane < D) ? lane : (D - 1);
    const int   nd = paths[(size_t)c * D + dd];   // lane d holds path[d]
    const float cd = codes[(size_t)c * D + dd];   // lane d holds code[d]
    const float bv = bias[nd];                    // lane d holds bias[path[d]]
    const float sd = 1.0f - 2.0f * cd;            // sign for fused sigmoid

    float acc[D];
    #pragma unroll
    for (int d = 0; d < D; ++d) {
        const int node = __shfl(nd, d, 64);       // uniform broadcast
        const float4* wr = reinterpret_cast<const float4*>(W + (size_t)node * I);
        const float4 wa = wr[lane];
        const float4 wb = wr[lane + 64];
        acc[d] = xa.x * wa.x + xa.y * wa.y + xa.z * wa.z + xa.w * wa.w
               + xb.x * wb.x + xb.y * wb.y + xb.z * wb.z + xb.w * wb.w;
    }

    // batched butterfly: D interleaved 6-step chains
    #pragma unroll
    for (int off = 32; off; off >>= 1) {
        #pragma unroll
        for (int d = 0; d < D; ++d)
            acc[d] += __shfl_xor(acc[d], off, 64);
    }

    // Q = prod(1 + exp(-s_d * t_d));  out = 1/Q
    float q = 1.0f;
    #pragma unroll
    for (int d = 0; d < D; ++d) {
        const float t = acc[d] + __shfl(bv, d, 64);
        const float s = __shfl(sd, d, 64);
        q *= 1.0f + __expf(-s * t);
    }
    if (lane == 0) out[p] = 1.0f / q;
}

// Generic fallback for unexpected depths (correct, round-1 structure).
__global__ __launch_bounds__(WPB * 64)
void huff_kernel_gen(const float* __restrict__ x, const int* __restrict__ tgt,
                     const float* __restrict__ W, const float* __restrict__ bias,
                     const int* __restrict__ paths, const float* __restrict__ codes,
                     float* __restrict__ out, int R, int I, int D, int npairs)
{
    const int lane = threadIdx.x & 63;
    const int p = blockIdx.x * WPB + (threadIdx.x >> 6);
    if (p >= npairs) return;
    const int b = p / R;
    const float4* xrow = reinterpret_cast<const float4*>(x + (size_t)b * I);
    const float4 xa = xrow[lane];
    const float4 xb = xrow[lane + 64];
    const int c = tgt[p];
    float q = 1.0f;
    for (int d = 0; d < D; ++d) {
        const int node = paths[(size_t)c * D + d];
        const float4* wr = reinterpret_cast<const float4*>(W + (size_t)node * I);
        const float4 wa = wr[lane];
        const float4 wb = wr[lane + 64];
        float acc = xa.x * wa.x + xa.y * wa.y + xa.z * wa.z + xa.w * wa.w
                  + xb.x * wb.x + xb.y * wb.y + xb.z * wb.z + xb.w * wb.w;
        #pragma unroll
        for (int off = 32; off; off >>= 1) acc += __shfl_xor(acc, off, 64);
        const float t = acc + bias[node];
        const float s = 1.0f - 2.0f * codes[(size_t)c * D + d];
        q *= 1.0f + __expf(-s * t);
    }
    if (lane == 0) out[p] = 1.0f / q;
}

extern "C" void kernel_launch(void* const* d_in, const int* in_sizes, int n_in,
                              void* d_out, int out_size, void* d_ws, size_t ws_size,
                              hipStream_t stream) {
    const float* x     = (const float*)d_in[0];
    const int*   tgt   = (const int*)  d_in[1];
    const float* W     = (const float*)d_in[2];
    const float* bias  = (const float*)d_in[3];
    const int*   paths = (const int*)  d_in[4];
    const float* codes = (const float*)d_in[5];
    float* out = (float*)d_out;

    const int N = in_sizes[3];            // total_nodes = nb_classes - 1
    const int C = N + 1;                  // nb_classes
    const int I = in_sizes[2] / N;        // input dim (512)
    const int B = in_sizes[0] / I;        // batch (1024)
    const int R = in_sizes[1] / B;        // requests (8)
    const int D = in_sizes[4] / C;        // max path depth

    const int npairs = B * R;
    const int grid = (npairs + WPB - 1) / WPB;

    switch (D) {
    case 15: huff_kernel<15><<<grid, WPB * 64, 0, stream>>>(x, tgt, W, bias, paths, codes, out, R, I, npairs); break;
    case 16: huff_kernel<16><<<grid, WPB * 64, 0, stream>>>(x, tgt, W, bias, paths, codes, out, R, I, npairs); break;
    case 17: huff_kernel<17><<<grid, WPB * 64, 0, stream>>>(x, tgt, W, bias, paths, codes, out, R, I, npairs); break;
    case 18: huff_kernel<18><<<grid, WPB * 64, 0, stream>>>(x, tgt, W, bias, paths, codes, out, R, I, npairs); break;
    default: huff_kernel_gen<<<grid, WPB * 64, 0, stream>>>(x, tgt, W, bias, paths, codes, out, R, I, D, npairs); break;
    }
}